// Round 3
// baseline (261.038 us; speedup 1.0000x reference)
//
#include <hip/hip_runtime.h>

#define N_FLOWS 20
#define DIM 4
#define ITEMS 8
#define BLOCK 256

typedef float v2f __attribute__((ext_vector_type(2)));

// ---------------------------------------------------------------------------
// Setup: one tiny block computes softplus params once.
// ws layout per flow f (8 floats, 32B): [x0.x,x0.y,x0.z,x0.w, alpha, beta, 0,0]
// ---------------------------------------------------------------------------
__global__ void radial_setup(const float* __restrict__ x0s,
                             const float* __restrict__ alpha_primes,
                             const float* __restrict__ beta_primes,
                             float* __restrict__ ws) {
    int f = threadIdx.x;
    if (f < N_FLOWS) {
        float alpha = __logf(1.0f + __expf(alpha_primes[f]));
        float beta  = __logf(1.0f + __expf(beta_primes[f])) - alpha;
        float* p = ws + 8 * f;
        p[0] = x0s[4 * f + 0];
        p[1] = x0s[4 * f + 1];
        p[2] = x0s[4 * f + 2];
        p[3] = x0s[4 * f + 3];
        p[4] = alpha;
        p[5] = beta;
        p[6] = 0.0f;
        p[7] = 0.0f;
    }
}

// ---------------------------------------------------------------------------
// Main: 20 chained radial flows, packed fp32 body (v_pk_*), trans floor =
// 2 x quarter-rate ops per flow-item. R2 lesson: per-flow param loads inside
// the loop stall all resident waves (~40% VALU idle) -> double-buffer the
// params through registers so flow f+1's load is in flight during flow f's
// ~400-cycle item loop.
// ---------------------------------------------------------------------------
__global__ __launch_bounds__(BLOCK) void radial_main(
    const float4* __restrict__ Xv,
    const float4* __restrict__ P,   // P[2f]=x0, P[2f+1]={alpha,beta,_,_}
    float4* __restrict__ Ov)
{
    const unsigned base = blockIdx.x * (BLOCK * ITEMS) + threadIdx.x;

    // Flow-0 params issued BEFORE the X burst: latency overlaps the loads.
    float4 c  = P[0];
    float4 ab = P[1];

    v2f a[ITEMS], b[ITEMS];
#pragma unroll
    for (int i = 0; i < ITEMS; ++i) {
        float4 v = Xv[base + i * BLOCK];
        a[i] = (v2f){v.x, v.y};
        b[i] = (v2f){v.z, v.w};
    }

#pragma unroll
    for (int f = 0; f < N_FLOWS; ++f) {
        // Prefetch next flow's params; waitcnt lands after the item loop.
        float4 cn, abn;
        if (f + 1 < N_FLOWS) {
            cn  = P[2 * f + 2];
            abn = P[2 * f + 3];
        }
        v2f c01 = (v2f){c.x, c.y};
        v2f c23 = (v2f){c.z, c.w};
        float alpha = ab.x, beta = ab.y;
#pragma unroll
        for (int i = 0; i < ITEMS; ++i) {
            v2f da = a[i] - c01;          // v_pk_add_f32
            v2f db = b[i] - c23;
            v2f q  = da * da;             // v_pk_mul_f32
            q += db * db;                 // v_pk_fma_f32
            float r2 = q.x + q.y;
            float r  = __builtin_amdgcn_sqrtf(r2);              // quarter-rate
            float t  = beta * __builtin_amdgcn_rcpf(alpha + r); // quarter-rate
            v2f tv = (v2f){t, t};
            a[i] = tv * da + a[i];        // v_pk_fma_f32
            b[i] = tv * db + b[i];
        }
        if (f + 1 < N_FLOWS) {
            c  = cn;
            ab = abn;
        }
    }

#pragma unroll
    for (int i = 0; i < ITEMS; ++i) {
        float4 v;
        v.x = a[i].x; v.y = a[i].y; v.z = b[i].x; v.w = b[i].y;
        Ov[base + i * BLOCK] = v;
    }
}

// Generic tail (grid 0 for BATCH=2^23; kept for generality).
__global__ void radial_tail(const float4* __restrict__ Xv,
                            const float4* __restrict__ P,
                            float4* __restrict__ Ov,
                            int start, int batch)
{
    int idx = start + blockIdx.x * blockDim.x + threadIdx.x;
    if (idx >= batch) return;
    float4 v = Xv[idx];
#pragma unroll
    for (int f = 0; f < N_FLOWS; ++f) {
        float4 c  = P[2 * f];
        float4 ab = P[2 * f + 1];
        float dx = v.x - c.x, dy = v.y - c.y, dz = v.z - c.z, dw = v.w - c.w;
        float r2 = dx * dx + dy * dy + dz * dz + dw * dw;
        float r  = __builtin_amdgcn_sqrtf(r2);
        float t  = ab.y * __builtin_amdgcn_rcpf(ab.x + r);
        v.x += t * dx; v.y += t * dy; v.z += t * dz; v.w += t * dw;
    }
    Ov[idx] = v;
}

extern "C" void kernel_launch(void* const* d_in, const int* in_sizes, int n_in,
                              void* d_out, int out_size, void* d_ws, size_t ws_size,
                              hipStream_t stream) {
    const float* X   = (const float*)d_in[0];
    const float* x0s = (const float*)d_in[1];
    const float* ap  = (const float*)d_in[2];
    const float* bp  = (const float*)d_in[3];
    float* out = (float*)d_out;
    float* ws  = (float*)d_ws;

    int batch = in_sizes[0] / DIM; // 8388608

    radial_setup<<<1, 64, 0, stream>>>(x0s, ap, bp, ws);

    const int tile = BLOCK * ITEMS;
    int full_blocks = batch / tile;
    if (full_blocks > 0)
        radial_main<<<full_blocks, BLOCK, 0, stream>>>(
            (const float4*)X, (const float4*)ws, (float4*)out);

    int done = full_blocks * tile;
    int rem = batch - done;
    if (rem > 0)
        radial_tail<<<(rem + 255) / 256, 256, 0, stream>>>(
            (const float4*)X, (const float4*)ws, (float4*)out, done, batch);
}